// Round 5
// baseline (3120.503 us; speedup 1.0000x reference)
//
#include <hip/hip_runtime.h>
#include <hip/hip_bf16.h>

typedef __hip_bfloat16 bf16;

#define N0c 331776
#define N1c 36864
#define N2c 4096
#define E0c 294912
#define E1c 32768

// ---------- helpers ----------
__device__ __forceinline__ float bfbits2f(unsigned short b) {
    union { unsigned u; float f; } x; x.u = ((unsigned)b) << 16; return x.f;
}
__device__ __forceinline__ unsigned short f2bfbits(float f) {
    bf16 h = __float2bfloat16(f);
    return *reinterpret_cast<unsigned short*>(&h);
}
__device__ __forceinline__ float bf2f(const bf16* p) {
    return bfbits2f(*reinterpret_cast<const unsigned short*>(p));
}
__device__ __forceinline__ void load4f(const float* p, float* o) {
    const float4 v = *reinterpret_cast<const float4*>(p);
    o[0] = v.x; o[1] = v.y; o[2] = v.z; o[3] = v.w;
}
__device__ __forceinline__ void load4b(const bf16* p, float* o) {
    const ushort4 v = *reinterpret_cast<const ushort4*>(p);
    o[0] = bfbits2f(v.x); o[1] = bfbits2f(v.y); o[2] = bfbits2f(v.z); o[3] = bfbits2f(v.w);
}
__device__ __forceinline__ void load4x(const float* p, float* o) { load4f(p, o); }
__device__ __forceinline__ void load4x(const bf16* p, float* o)  { load4b(p, o); }
__device__ __forceinline__ void store_c(float* p, float v) { *p = v; }
__device__ __forceinline__ void store_c(bf16* p, float v)  { *p = __float2bfloat16(v); }

// ---------- tiled GEMM: C = act(A[M,K] @ B[K,N] + bias[N]); A,B,bias fp32 ----------
template<typename TC, bool RELU>
__global__ __launch_bounds__(256) void gemm_tiled(
    const float* __restrict__ A, const float* __restrict__ B,
    const float* __restrict__ bias, TC* __restrict__ C,
    int M, int N, int K)
{
    __shared__ float As[64][17];
    __shared__ float Bs[16][65];

    const int tid = threadIdx.x;
    const int tx = tid & 15, ty = tid >> 4;
    const int row0 = blockIdx.y * 64, col0 = blockIdx.x * 64;

    const int ar = tid >> 2;
    const int ac = (tid & 3) * 4;
    const int br = tid >> 4;
    const int bc = (tid & 15) * 4;

    float acc[4][4] = {};

    for (int k0 = 0; k0 < K; k0 += 16) {
        float a4[4], b4[4];
        load4f(A + (size_t)(row0 + ar) * K + k0 + ac, a4);
        As[ar][ac+0]=a4[0]; As[ar][ac+1]=a4[1]; As[ar][ac+2]=a4[2]; As[ar][ac+3]=a4[3];
        load4f(B + (size_t)(k0 + br) * N + col0 + bc, b4);
        Bs[br][bc+0]=b4[0]; Bs[br][bc+1]=b4[1]; Bs[br][bc+2]=b4[2]; Bs[br][bc+3]=b4[3];
        __syncthreads();
        #pragma unroll
        for (int kk = 0; kk < 16; ++kk) {
            float a[4], b[4];
            #pragma unroll
            for (int i = 0; i < 4; ++i) a[i] = As[ty*4+i][kk];
            #pragma unroll
            for (int j = 0; j < 4; ++j) b[j] = Bs[kk][tx*4+j];
            #pragma unroll
            for (int i = 0; i < 4; ++i)
                #pragma unroll
                for (int j = 0; j < 4; ++j)
                    acc[i][j] = fmaf(a[i], b[j], acc[i][j]);
        }
        __syncthreads();
    }
    #pragma unroll
    for (int i = 0; i < 4; ++i) {
        const int r = row0 + ty*4 + i;
        #pragma unroll
        for (int j = 0; j < 4; ++j) {
            const int c = col0 + tx*4 + j;
            float v = acc[i][j] + bias[c];
            if (RELU) v = fmaxf(v, 0.f);
            store_c(C + (size_t)r * N + c, v);
        }
    }
}

// ---------- fused-concat GEMM: A row r = [m[r,0:512] | hdst[r,0:256]], K=768 ----------
template<typename TC, bool RELU>
__global__ __launch_bounds__(256) void gemm_concat(
    const float* __restrict__ m, const bf16* __restrict__ hdst,
    const float* __restrict__ B, const float* __restrict__ bias,
    TC* __restrict__ C, int M, int N)
{
    __shared__ float As[64][17];
    __shared__ float Bs[16][65];

    const int tid = threadIdx.x;
    const int tx = tid & 15, ty = tid >> 4;
    const int row0 = blockIdx.y * 64, col0 = blockIdx.x * 64;

    const int ar = tid >> 2;
    const int ac = (tid & 3) * 4;
    const int br = tid >> 4;
    const int bc = (tid & 15) * 4;

    float acc[4][4] = {};

    for (int k0 = 0; k0 < 768; k0 += 16) {
        float a4[4], b4[4];
        if (k0 < 512) load4f(m + (size_t)(row0 + ar) * 512 + k0 + ac, a4);
        else          load4b(hdst + (size_t)(row0 + ar) * 256 + (k0 - 512) + ac, a4);
        As[ar][ac+0]=a4[0]; As[ar][ac+1]=a4[1]; As[ar][ac+2]=a4[2]; As[ar][ac+3]=a4[3];
        load4f(B + (size_t)(k0 + br) * N + col0 + bc, b4);
        Bs[br][bc+0]=b4[0]; Bs[br][bc+1]=b4[1]; Bs[br][bc+2]=b4[2]; Bs[br][bc+3]=b4[3];
        __syncthreads();
        #pragma unroll
        for (int kk = 0; kk < 16; ++kk) {
            float a[4], b[4];
            #pragma unroll
            for (int i = 0; i < 4; ++i) a[i] = As[ty*4+i][kk];
            #pragma unroll
            for (int j = 0; j < 4; ++j) b[j] = Bs[kk][tx*4+j];
            #pragma unroll
            for (int i = 0; i < 4; ++i)
                #pragma unroll
                for (int j = 0; j < 4; ++j)
                    acc[i][j] = fmaf(a[i], b[j], acc[i][j]);
        }
        __syncthreads();
    }
    #pragma unroll
    for (int i = 0; i < 4; ++i) {
        const int r = row0 + ty*4 + i;
        #pragma unroll
        for (int j = 0; j < 4; ++j) {
            const int c = col0 + tx*4 + j;
            float v = acc[i][j] + bias[c];
            if (RELU) v = fmaxf(v, 0.f);
            store_c(C + (size_t)r * N + c, v);
        }
    }
}

// ---------- layer-1 fused edge kernel: 64 edges/block ----------
// gather feat0[src] -> h = X@Wp+bp (bf16 LDS) -> n = relu(h@Q1+bq1) -> scatter m1,ws0
__global__ __launch_bounds__(256) void edge1_kernel(
    const float* __restrict__ feat0, const float* __restrict__ Wp,
    const float* __restrict__ bp, const float* __restrict__ Q1,
    const float* __restrict__ bq1,
    const int* __restrict__ src, const int* __restrict__ dst,
    const float* __restrict__ w,
    float* __restrict__ m, float* __restrict__ wsum)
{
    __shared__ float Xs[64][129];     // 33.0 KB
    __shared__ bf16  Hs[64][264];     // 33.8 KB (cols 0..255 used)
    __shared__ float Bs[16][65];      //  4.2 KB
    __shared__ int   dsts[64];
    __shared__ float wts[64];

    const int tid = threadIdx.x;
    const size_t e0 = (size_t)blockIdx.x * 64;

    if (tid < 64) { dsts[tid] = dst[e0 + tid]; wts[tid] = w[e0 + tid]; }

    {   // gather: thread t -> row r=t>>2, quarter q=t&3 (32 floats, contiguous)
        const int r = tid >> 2, q = tid & 3;
        const int s = src[e0 + r];
        const float* fr = feat0 + (size_t)s * 128 + q * 32;
        #pragma unroll
        for (int i = 0; i < 8; ++i) {
            const float4 v = *reinterpret_cast<const float4*>(fr + i * 4);
            Xs[r][q*32 + i*4 + 0] = v.x; Xs[r][q*32 + i*4 + 1] = v.y;
            Xs[r][q*32 + i*4 + 2] = v.z; Xs[r][q*32 + i*4 + 3] = v.w;
        }
    }
    __syncthreads();

    const int tx = tid & 15, ty = tid >> 4;
    const int br = tid >> 4, bc = (tid & 15) * 4;

    // phase 2: Hs = Xs @ Wp + bp   (4 col-passes of 64; K=128)
    for (int p = 0; p < 4; ++p) {
        float acc[4][4] = {};
        for (int k0 = 0; k0 < 128; k0 += 16) {
            const float4 v = *reinterpret_cast<const float4*>(
                Wp + (size_t)(k0 + br) * 256 + p * 64 + bc);
            Bs[br][bc+0]=v.x; Bs[br][bc+1]=v.y; Bs[br][bc+2]=v.z; Bs[br][bc+3]=v.w;
            __syncthreads();
            #pragma unroll
            for (int kk = 0; kk < 16; ++kk) {
                float a[4], b[4];
                #pragma unroll
                for (int i = 0; i < 4; ++i) a[i] = Xs[ty*4+i][k0+kk];
                #pragma unroll
                for (int j = 0; j < 4; ++j) b[j] = Bs[kk][tx*4+j];
                #pragma unroll
                for (int i = 0; i < 4; ++i)
                    #pragma unroll
                    for (int j = 0; j < 4; ++j)
                        acc[i][j] = fmaf(a[i], b[j], acc[i][j]);
            }
            __syncthreads();
        }
        #pragma unroll
        for (int i = 0; i < 4; ++i)
            #pragma unroll
            for (int j = 0; j < 4; ++j) {
                const int c = p*64 + tx*4 + j;
                Hs[ty*4+i][c] = __float2bfloat16(acc[i][j] + bp[c]);
            }
    }
    __syncthreads();

    // phase 3: n = relu(Hs @ Q1 + bq1) and scatter (8 col-passes of 64; K=256)
    for (int p = 0; p < 8; ++p) {
        float acc[4][4] = {};
        for (int k0 = 0; k0 < 256; k0 += 16) {
            const float4 v = *reinterpret_cast<const float4*>(
                Q1 + (size_t)(k0 + br) * 512 + p * 64 + bc);
            Bs[br][bc+0]=v.x; Bs[br][bc+1]=v.y; Bs[br][bc+2]=v.z; Bs[br][bc+3]=v.w;
            __syncthreads();
            #pragma unroll
            for (int kk = 0; kk < 16; ++kk) {
                float a[4], b[4];
                #pragma unroll
                for (int i = 0; i < 4; ++i) a[i] = bf2f(&Hs[ty*4+i][k0+kk]);
                #pragma unroll
                for (int j = 0; j < 4; ++j) b[j] = Bs[kk][tx*4+j];
                #pragma unroll
                for (int i = 0; i < 4; ++i)
                    #pragma unroll
                    for (int j = 0; j < 4; ++j)
                        acc[i][j] = fmaf(a[i], b[j], acc[i][j]);
            }
            __syncthreads();
        }
        #pragma unroll
        for (int i = 0; i < 4; ++i) {
            const int d = dsts[ty*4+i];
            const float wt = wts[ty*4+i];
            #pragma unroll
            for (int j = 0; j < 4; ++j) {
                const int c = p*64 + tx*4 + j;
                const float n = fmaxf(acc[i][j] + bq1[c], 0.f);
                atomicAdd(&m[(size_t)d * 512 + c], n * wt);
            }
        }
    }
    if (tid < 64) atomicAdd(&wsum[dsts[tid]], wts[tid]);
}

// ---------- layer-2 fused edge kernel: gather z1n[src] (bf16) -> relu(Z@Q2+bq2) -> scatter ----------
__global__ __launch_bounds__(256) void edge2_kernel(
    const bf16* __restrict__ zn, const float* __restrict__ Q2,
    const float* __restrict__ bq2,
    const int* __restrict__ src, const int* __restrict__ dst,
    const float* __restrict__ w,
    float* __restrict__ m, float* __restrict__ wsum)
{
    __shared__ bf16  Zs[64][264];
    __shared__ float Bs[16][65];
    __shared__ int   dsts[64];
    __shared__ float wts[64];

    const int tid = threadIdx.x;
    const size_t e0 = (size_t)blockIdx.x * 64;

    if (tid < 64) { dsts[tid] = dst[e0 + tid]; wts[tid] = w[e0 + tid]; }

    {   // gather: thread t -> row r=t>>2, quarter q=t&3 (64 bf16, contiguous, full coverage)
        const int r = tid >> 2, q = tid & 3;
        const int s = src[e0 + r];
        const bf16* zr = zn + (size_t)s * 256 + q * 64;
        #pragma unroll
        for (int i = 0; i < 16; ++i) {
            const ushort4 v = *reinterpret_cast<const ushort4*>(zr + i * 4);
            unsigned short* o = reinterpret_cast<unsigned short*>(&Zs[r][q*64 + i*4]);
            o[0] = v.x; o[1] = v.y; o[2] = v.z; o[3] = v.w;
        }
    }
    __syncthreads();

    const int tx = tid & 15, ty = tid >> 4;
    const int br = tid >> 4, bc = (tid & 15) * 4;

    for (int p = 0; p < 8; ++p) {
        float acc[4][4] = {};
        for (int k0 = 0; k0 < 256; k0 += 16) {
            const float4 v = *reinterpret_cast<const float4*>(
                Q2 + (size_t)(k0 + br) * 512 + p * 64 + bc);
            Bs[br][bc+0]=v.x; Bs[br][bc+1]=v.y; Bs[br][bc+2]=v.z; Bs[br][bc+3]=v.w;
            __syncthreads();
            #pragma unroll
            for (int kk = 0; kk < 16; ++kk) {
                float a[4], b[4];
                #pragma unroll
                for (int i = 0; i < 4; ++i) a[i] = bf2f(&Zs[ty*4+i][k0+kk]);
                #pragma unroll
                for (int j = 0; j < 4; ++j) b[j] = Bs[kk][tx*4+j];
                #pragma unroll
                for (int i = 0; i < 4; ++i)
                    #pragma unroll
                    for (int j = 0; j < 4; ++j)
                        acc[i][j] = fmaf(a[i], b[j], acc[i][j]);
            }
            __syncthreads();
        }
        #pragma unroll
        for (int i = 0; i < 4; ++i) {
            const int d = dsts[ty*4+i];
            const float wt = wts[ty*4+i];
            #pragma unroll
            for (int j = 0; j < 4; ++j) {
                const int c = p*64 + tx*4 + j;
                const float n = fmaxf(acc[i][j] + bq2[c], 0.f);
                atomicAdd(&m[(size_t)d * 512 + c], n * wt);
            }
        }
    }
    if (tid < 64) atomicAdd(&wsum[dsts[tid]], wts[tid]);
}

// ---------- scale rows: m[r,:] *= 1/max(ws[r],1) ----------
__global__ __launch_bounds__(256) void scale_rows(
    float* __restrict__ m, const float* __restrict__ wsum)
{
    const int row = blockIdx.x;
    const float inv = 1.f / fmaxf(wsum[row], 1.f);
    float* p = m + (size_t)row * 512;
    #pragma unroll
    for (int c = threadIdx.x; c < 512; c += 256) p[c] *= inv;
}

// ---------- l2 normalize rows of Z [rows,256] -> bf16 out ----------
template<typename TZ>
__global__ __launch_bounds__(256) void l2norm_kernel(
    const TZ* __restrict__ Z, bf16* __restrict__ out, int rows)
{
    const int wave = threadIdx.x >> 6, lane = threadIdx.x & 63;
    const int row = blockIdx.x * 4 + wave;
    if (row >= rows) return;
    float v[4];
    load4x(Z + (size_t)row * 256 + lane * 4, v);
    float ss = v[0]*v[0] + v[1]*v[1] + v[2]*v[2] + v[3]*v[3];
    #pragma unroll
    for (int off = 32; off; off >>= 1) ss += __shfl_xor(ss, off, 64);
    const float scale = (ss == 0.f) ? 1.f : (1.f / sqrtf(ss));
    ushort4 o;
    o.x = f2bfbits(v[0]*scale); o.y = f2bfbits(v[1]*scale);
    o.z = f2bfbits(v[2]*scale); o.w = f2bfbits(v[3]*scale);
    *reinterpret_cast<ushort4*>(out + (size_t)row * 256 + lane * 4) = o;
}

// ---------- l2 normalize + skip add: out = P + Z/||Z|| (fp32) ----------
__global__ __launch_bounds__(256) void l2norm_add_kernel(
    const float* __restrict__ Z, const float* __restrict__ P,
    float* __restrict__ out, int rows)
{
    const int wave = threadIdx.x >> 6, lane = threadIdx.x & 63;
    const int row = blockIdx.x * 4 + wave;
    if (row >= rows) return;
    float v[4];
    load4f(Z + (size_t)row * 256 + lane * 4, v);
    float ss = v[0]*v[0] + v[1]*v[1] + v[2]*v[2] + v[3]*v[3];
    #pragma unroll
    for (int off = 32; off; off >>= 1) ss += __shfl_xor(ss, off, 64);
    const float scale = (ss == 0.f) ? 1.f : (1.f / sqrtf(ss));
    float p[4];
    load4f(P + (size_t)row * 256 + lane * 4, p);
    float4 o;
    o.x = p[0] + v[0]*scale; o.y = p[1] + v[1]*scale;
    o.z = p[2] + v[2]*scale; o.w = p[3] + v[3]*scale;
    *reinterpret_cast<float4*>(out + (size_t)row * 256 + lane * 4) = o;
}

// ---------- scoring: wave per edge; e<4096 -> pos, else neg. OUTPUT IS FP32 ----------
__global__ __launch_bounds__(256) void score_kernel(
    const float* __restrict__ h,
    const int* __restrict__ ps, const int* __restrict__ pdi,
    const int* __restrict__ ns, const int* __restrict__ nd,
    const int* __restrict__ nid, const float* __restrict__ bias,
    float* __restrict__ out)
{
    const int wave = threadIdx.x >> 6, lane = threadIdx.x & 63;
    const int e = blockIdx.x * 4 + wave;
    const int ei = e & 4095;
    const int s = (e < 4096) ? ps[ei] : ns[ei];
    const int d = (e < 4096) ? pdi[ei] : nd[ei];
    float a[4], b[4];
    load4f(h + (size_t)s * 256 + lane * 4, a);
    load4f(h + (size_t)d * 256 + lane * 4, b);
    float dot = a[0]*b[0] + a[1]*b[1] + a[2]*b[2] + a[3]*b[3];
    #pragma unroll
    for (int off = 32; off; off >>= 1) dot += __shfl_xor(dot, off, 64);
    if (lane == 0)
        out[e] = dot + bias[nid[s]] + bias[nid[d]];
}

// ---------- launcher ----------
extern "C" void kernel_launch(void* const* d_in, const int* in_sizes, int n_in,
                              void* d_out, int out_size, void* d_ws, size_t ws_size,
                              hipStream_t stream)
{
    const float* feat0    = (const float*)d_in[0];
    const float* feat_dst = (const float*)d_in[1];
    const float* weights0 = (const float*)d_in[2];
    const float* weights1 = (const float*)d_in[3];
    const float* W_proj   = (const float*)d_in[4];
    const float* b_proj   = (const float*)d_in[5];
    const float* Q1       = (const float*)d_in[6];
    const float* bq1      = (const float*)d_in[7];
    const float* W1       = (const float*)d_in[8];
    const float* bw1      = (const float*)d_in[9];
    const float* Q2       = (const float*)d_in[10];
    const float* bq2      = (const float*)d_in[11];
    const float* W2       = (const float*)d_in[12];
    const float* bw2      = (const float*)d_in[13];
    const float* biasN    = (const float*)d_in[14];
    const int* b0s = (const int*)d_in[15];
    const int* b0d = (const int*)d_in[16];
    const int* b1s = (const int*)d_in[17];
    const int* b1d = (const int*)d_in[18];
    const int* pos_src = (const int*)d_in[19];
    const int* pos_dst = (const int*)d_in[20];
    const int* neg_src = (const int*)d_in[21];
    const int* neg_dst = (const int*)d_in[22];
    const int* nid     = (const int*)d_in[23];

    // ---- workspace layout (peak ~108.2 MiB) ----
    char* ws = (char*)d_ws;
    size_t off = 0;
    auto alloc = [&](size_t bytes) -> void* {
        void* p = ws + off; off += (bytes + 255) & ~(size_t)255; return p;
    };
    float* m1    = (float*)alloc((size_t)N1c * 512 * 4);  // 75.50 MB (region1)
    bf16*  h1dst = (bf16*) alloc((size_t)N1c * 256 * 2);  // 18.87 MB (region2)
    bf16*  z1b   = (bf16*) alloc((size_t)N1c * 256 * 2);  // 18.87 MB
    float* ws0   = (float*)alloc((size_t)N1c * 4);        //  0.15 MB

    // region1 reuse for layer 2 (m1 dead after W1-GEMM):
    char* r1 = (char*)m1;
    float* m2     = (float*)r1;                                   //  8.39 MB
    float* ws1    = (float*)(r1 + (size_t)N2c * 512 * 4);         //  16 KB
    float* z2     = (float*)(r1 + (size_t)N2c * 512 * 4 + 65536); //  4 MB
    float* pdbuf  = z2 + (size_t)N2c * 256;                       //  4 MB
    float* h_item = pdbuf + (size_t)N2c * 256;                    //  4 MB
    // region2 reuse: z1n aliases h1dst (h1dst dead after W1-GEMM)
    bf16* z1n = h1dst;

    // ---- layer 1 ----
    hipMemsetAsync(m1,  0, (size_t)N1c * 512 * 4, stream);
    hipMemsetAsync(ws0, 0, (size_t)N1c * 4,       stream);

    // h_dst for layer-1 concat: proj of first N1 rows of feat0
    gemm_tiled<bf16, false><<<dim3(256/64, N1c/64), 256, 0, stream>>>(
        feat0, W_proj, b_proj, h1dst, N1c, 256, 128);

    // fused gather->proj->Q1->relu->scatter over E0 edges
    edge1_kernel<<<E0c/64, 256, 0, stream>>>(
        feat0, W_proj, b_proj, Q1, bq1, b0s, b0d, weights0, m1, ws0);

    scale_rows<<<N1c, 256, 0, stream>>>(m1, ws0);

    gemm_concat<bf16, true><<<dim3(256/64, N1c/64), 256, 0, stream>>>(
        m1, h1dst, W1, bw1, z1b, N1c, 256);

    l2norm_kernel<bf16><<<N1c/4, 256, 0, stream>>>(z1b, z1n, N1c);  // z1n overwrites h1dst (dead)

    // ---- layer 2 (region1 now reusable) ----
    hipMemsetAsync(m2,  0, (size_t)N2c * 512 * 4, stream);
    hipMemsetAsync(ws1, 0, (size_t)N2c * 4,       stream);

    edge2_kernel<<<E1c/64, 256, 0, stream>>>(
        z1n, Q2, bq2, b1s, b1d, weights1, m2, ws1);

    scale_rows<<<N2c, 256, 0, stream>>>(m2, ws1);

    gemm_concat<float, true><<<dim3(256/64, N2c/64), 256, 0, stream>>>(
        m2, z1n, W2, bw2, z2, N2c, 256);

    gemm_tiled<float, false><<<dim3(256/64, N2c/64), 256, 0, stream>>>(
        feat_dst, W_proj, b_proj, pdbuf, N2c, 256, 128);

    l2norm_add_kernel<<<N2c/4, 256, 0, stream>>>(z2, pdbuf, h_item, N2c);

    score_kernel<<<2048, 256, 0, stream>>>(
        h_item, pos_src, pos_dst, neg_src, neg_dst, nid, biasN, (float*)d_out);
}

// Round 6
// 741.535 us; speedup vs baseline: 4.2082x; 4.2082x over previous
//
#include <hip/hip_runtime.h>
#include <hip/hip_bf16.h>

typedef __hip_bfloat16 bf16;
typedef __attribute__((ext_vector_type(8))) short frag8;   // 8 bf16 = 4 VGPR (MFMA A/B)
typedef __attribute__((ext_vector_type(4))) float f32x4;   // MFMA C/D

#define N0c 331776
#define N1c 36864
#define N2c 4096
#define E0c 294912
#define E1c 32768

// ---------- helpers ----------
__device__ __forceinline__ float bfbits2f(unsigned short b) {
    union { unsigned u; float f; } x; x.u = ((unsigned)b) << 16; return x.f;
}
__device__ __forceinline__ unsigned short f2bfbits(float f) {
    bf16 h = __float2bfloat16(f);
    return *reinterpret_cast<unsigned short*>(&h);
}
__device__ __forceinline__ void load4f(const float* p, float* o) {
    const float4 v = *reinterpret_cast<const float4*>(p);
    o[0] = v.x; o[1] = v.y; o[2] = v.z; o[3] = v.w;
}
__device__ __forceinline__ ushort4 pack4(float4 v) {
    ushort4 o; o.x = f2bfbits(v.x); o.y = f2bfbits(v.y);
    o.z = f2bfbits(v.z); o.w = f2bfbits(v.w); return o;
}
__device__ __forceinline__ void store_c(float* p, float v) { *p = v; }
__device__ __forceinline__ void store_c(bf16* p, float v)  { *p = __float2bfloat16(v); }
__device__ __forceinline__ f32x4 zero4() {
    f32x4 z; z[0] = 0.f; z[1] = 0.f; z[2] = 0.f; z[3] = 0.f; return z;
}
__device__ __forceinline__ f32x4 mfma16(frag8 a, frag8 b, f32x4 c) {
    return __builtin_amdgcn_mfma_f32_16x16x32_bf16(a, b, c, 0, 0, 0);
}

// ---------- prep: fp32 [K][N] -> bf16 transposed [N][K] ----------
__global__ __launch_bounds__(256) void transpose_bf16(
    const float* __restrict__ src, bf16* __restrict__ dst, int K, int N)
{
    const int idx = blockIdx.x * 256 + threadIdx.x;
    if (idx >= K * N) return;
    const int k = idx / N, n = idx - k * N;       // coalesced read
    dst[(size_t)n * K + k] = __float2bfloat16(src[idx]);
}

// ---------- MFMA proj GEMM: C[M,256] = A[M,128] @ Wp + bp ----------
// 64 rows/block, 4 waves (one per 64-col slab). BT = WpT[256][128] bf16.
template<typename TC>
__global__ __launch_bounds__(256) void gemm_mfma_proj(
    const float* __restrict__ A, const bf16* __restrict__ WpT,
    const float* __restrict__ bp, TC* __restrict__ C)
{
    __shared__ bf16 Xs[64 * 136];   // 128 + 8 pad

    const int tid = threadIdx.x;
    const int lane = tid & 63, wave = tid >> 6;
    const int row0 = blockIdx.x * 64;

    {   // stage A rows -> bf16 LDS
        const int r = tid >> 2, q = tid & 3;
        const float* ar = A + (size_t)(row0 + r) * 128 + q * 32;
        bf16* xr = Xs + r * 136 + q * 32;
        #pragma unroll
        for (int i = 0; i < 8; ++i)
            *reinterpret_cast<ushort4*>(xr + i * 4) =
                pack4(*reinterpret_cast<const float4*>(ar + i * 4));
    }
    __syncthreads();

    const int lr = lane & 15;
    const int lk = (lane >> 4) * 8;
    const int lm4 = (lane >> 4) * 4;

    f32x4 acc[4][4];
    #pragma unroll
    for (int mi = 0; mi < 4; ++mi)
        #pragma unroll
        for (int ni = 0; ni < 4; ++ni) acc[mi][ni] = zero4();

    #pragma unroll
    for (int kk = 0; kk < 4; ++kk) {
        frag8 a[4], b[4];
        #pragma unroll
        for (int mi = 0; mi < 4; ++mi)
            a[mi] = *reinterpret_cast<const frag8*>(&Xs[(mi * 16 + lr) * 136 + kk * 32 + lk]);
        #pragma unroll
        for (int ni = 0; ni < 4; ++ni)
            b[ni] = *reinterpret_cast<const frag8*>(
                WpT + (size_t)(wave * 64 + ni * 16 + lr) * 128 + kk * 32 + lk);
        #pragma unroll
        for (int mi = 0; mi < 4; ++mi)
            #pragma unroll
            for (int ni = 0; ni < 4; ++ni)
                acc[mi][ni] = mfma16(a[mi], b[ni], acc[mi][ni]);
    }

    #pragma unroll
    for (int ni = 0; ni < 4; ++ni) {
        const int c = wave * 64 + ni * 16 + lr;
        const float bb = bp[c];
        #pragma unroll
        for (int mi = 0; mi < 4; ++mi)
            #pragma unroll
            for (int i = 0; i < 4; ++i)
                store_c(C + (size_t)(row0 + mi * 16 + lm4 + i) * 256 + c,
                        acc[mi][ni][i] + bb);
    }
}

// ---------- MFMA concat GEMM: C[M,256] = relu([m/max(ws,1) | hdst] @ W + bias) ----------
// K=768 in 6 chunks of 128. WT[256][768] bf16.
template<typename TC>
__global__ __launch_bounds__(256) void gemm_mfma_concat(
    const float* __restrict__ m, const float* __restrict__ wsum,
    const bf16* __restrict__ hdst, const bf16* __restrict__ WT,
    const float* __restrict__ bias, TC* __restrict__ C)
{
    __shared__ bf16 As[64 * 136];

    const int tid = threadIdx.x;
    const int lane = tid & 63, wave = tid >> 6;
    const int row0 = blockIdx.x * 64;
    const int r = tid >> 2, q = tid & 3;
    const float inv = 1.f / fmaxf(wsum[row0 + r], 1.f);

    const int lr = lane & 15;
    const int lk = (lane >> 4) * 8;
    const int lm4 = (lane >> 4) * 4;

    f32x4 acc[4][4];
    #pragma unroll
    for (int mi = 0; mi < 4; ++mi)
        #pragma unroll
        for (int ni = 0; ni < 4; ++ni) acc[mi][ni] = zero4();

    #pragma unroll
    for (int ch = 0; ch < 6; ++ch) {
        // stage chunk ch (cols ch*128 .. +127 of the virtual concat row)
        bf16* xr = As + r * 136 + q * 32;
        if (ch < 4) {
            const float* srcp = m + (size_t)(row0 + r) * 512 + ch * 128 + q * 32;
            #pragma unroll
            for (int i = 0; i < 8; ++i) {
                float4 v = *reinterpret_cast<const float4*>(srcp + i * 4);
                v.x *= inv; v.y *= inv; v.z *= inv; v.w *= inv;
                *reinterpret_cast<ushort4*>(xr + i * 4) = pack4(v);
            }
        } else {
            const bf16* srcp = hdst + (size_t)(row0 + r) * 256 + (ch - 4) * 128 + q * 32;
            #pragma unroll
            for (int i = 0; i < 8; ++i)
                *reinterpret_cast<ushort4*>(xr + i * 4) =
                    *reinterpret_cast<const ushort4*>(srcp + i * 4);
        }
        __syncthreads();

        #pragma unroll
        for (int kk = 0; kk < 4; ++kk) {
            frag8 a[4], b[4];
            #pragma unroll
            for (int mi = 0; mi < 4; ++mi)
                a[mi] = *reinterpret_cast<const frag8*>(&As[(mi * 16 + lr) * 136 + kk * 32 + lk]);
            #pragma unroll
            for (int ni = 0; ni < 4; ++ni)
                b[ni] = *reinterpret_cast<const frag8*>(
                    WT + (size_t)(wave * 64 + ni * 16 + lr) * 768 + ch * 128 + kk * 32 + lk);
            #pragma unroll
            for (int mi = 0; mi < 4; ++mi)
                #pragma unroll
                for (int ni = 0; ni < 4; ++ni)
                    acc[mi][ni] = mfma16(a[mi], b[ni], acc[mi][ni]);
        }
        __syncthreads();
    }

    #pragma unroll
    for (int ni = 0; ni < 4; ++ni) {
        const int c = wave * 64 + ni * 16 + lr;
        const float bb = bias[c];
        #pragma unroll
        for (int mi = 0; mi < 4; ++mi)
            #pragma unroll
            for (int i = 0; i < 4; ++i)
                store_c(C + (size_t)(row0 + mi * 16 + lm4 + i) * 256 + c,
                        fmaxf(acc[mi][ni][i] + bb, 0.f));
    }
}

// ---------- layer-1 fused edge kernel (MFMA): 64 edges/block ----------
// gather feat0[src] -> H = X@Wp+bp (LDS bf16) -> relu(H@Q1+bq1) -> atomic scatter
__global__ __launch_bounds__(256) void edge1_mfma(
    const float* __restrict__ feat0, const bf16* __restrict__ WpT,
    const float* __restrict__ bp, const bf16* __restrict__ Q1T,
    const float* __restrict__ bq1,
    const int* __restrict__ src, const int* __restrict__ dst,
    const float* __restrict__ w,
    float* __restrict__ mout, float* __restrict__ wsum)
{
    __shared__ bf16 Xs[64 * 136];    // 17.4 KB
    __shared__ bf16 Hs[64 * 264];    // 33.8 KB
    __shared__ int   dsts[64];
    __shared__ float wts[64];

    const int tid = threadIdx.x;
    const int lane = tid & 63, wave = tid >> 6;
    const size_t e0 = (size_t)blockIdx.x * 64;

    if (tid < 64) { dsts[tid] = dst[e0 + tid]; wts[tid] = w[e0 + tid]; }

    {   // gather + convert
        const int r = tid >> 2, q = tid & 3;
        const int s = src[e0 + r];
        const float* fr = feat0 + (size_t)s * 128 + q * 32;
        bf16* xr = Xs + r * 136 + q * 32;
        #pragma unroll
        for (int i = 0; i < 8; ++i)
            *reinterpret_cast<ushort4*>(xr + i * 4) =
                pack4(*reinterpret_cast<const float4*>(fr + i * 4));
    }
    __syncthreads();

    const int lr = lane & 15;
    const int lk = (lane >> 4) * 8;
    const int lm4 = (lane >> 4) * 4;

    // phase B: Hs = Xs @ Wp + bp ; wave covers cols [wave*64, +64)
    {
        f32x4 acc[4][4];
        #pragma unroll
        for (int mi = 0; mi < 4; ++mi)
            #pragma unroll
            for (int ni = 0; ni < 4; ++ni) acc[mi][ni] = zero4();

        #pragma unroll
        for (int kk = 0; kk < 4; ++kk) {
            frag8 a[4], b[4];
            #pragma unroll
            for (int mi = 0; mi < 4; ++mi)
                a[mi] = *reinterpret_cast<const frag8*>(&Xs[(mi * 16 + lr) * 136 + kk * 32 + lk]);
            #pragma unroll
            for (int ni = 0; ni < 4; ++ni)
                b[ni] = *reinterpret_cast<const frag8*>(
                    WpT + (size_t)(wave * 64 + ni * 16 + lr) * 128 + kk * 32 + lk);
            #pragma unroll
            for (int mi = 0; mi < 4; ++mi)
                #pragma unroll
                for (int ni = 0; ni < 4; ++ni)
                    acc[mi][ni] = mfma16(a[mi], b[ni], acc[mi][ni]);
        }
        #pragma unroll
        for (int ni = 0; ni < 4; ++ni) {
            const int c = wave * 64 + ni * 16 + lr;
            const float bb = bp[c];
            #pragma unroll
            for (int mi = 0; mi < 4; ++mi)
                #pragma unroll
                for (int i = 0; i < 4; ++i)
                    Hs[(mi * 16 + lm4 + i) * 264 + c] =
                        __float2bfloat16(acc[mi][ni][i] + bb);
        }
    }
    __syncthreads();

    // phase C: relu(Hs @ Q1 + bq1) -> scatter ; wave covers cols [wave*128,+128) in 2 passes
    #pragma unroll
    for (int pass = 0; pass < 2; ++pass) {
        const int nc0 = wave * 128 + pass * 64;
        f32x4 acc[4][4];
        #pragma unroll
        for (int mi = 0; mi < 4; ++mi)
            #pragma unroll
            for (int ni = 0; ni < 4; ++ni) acc[mi][ni] = zero4();

        #pragma unroll
        for (int kk = 0; kk < 8; ++kk) {
            frag8 a[4], b[4];
            #pragma unroll
            for (int mi = 0; mi < 4; ++mi)
                a[mi] = *reinterpret_cast<const frag8*>(&Hs[(mi * 16 + lr) * 264 + kk * 32 + lk]);
            #pragma unroll
            for (int ni = 0; ni < 4; ++ni)
                b[ni] = *reinterpret_cast<const frag8*>(
                    Q1T + (size_t)(nc0 + ni * 16 + lr) * 256 + kk * 32 + lk);
            #pragma unroll
            for (int mi = 0; mi < 4; ++mi)
                #pragma unroll
                for (int ni = 0; ni < 4; ++ni)
                    acc[mi][ni] = mfma16(a[mi], b[ni], acc[mi][ni]);
        }
        #pragma unroll
        for (int ni = 0; ni < 4; ++ni) {
            const int c = nc0 + ni * 16 + lr;
            const float bb = bq1[c];
            #pragma unroll
            for (int mi = 0; mi < 4; ++mi)
                #pragma unroll
                for (int i = 0; i < 4; ++i) {
                    const int row = mi * 16 + lm4 + i;
                    const float val = fmaxf(acc[mi][ni][i] + bb, 0.f) * wts[row];
                    atomicAdd(&mout[(size_t)dsts[row] * 512 + c], val);
                }
        }
    }
    if (tid < 64) atomicAdd(&wsum[dsts[tid]], wts[tid]);
}

// ---------- layer-2 fused edge kernel (MFMA): gather z1n bf16 -> relu(Z@Q2+bq2) -> scatter ----------
__global__ __launch_bounds__(256) void edge2_mfma(
    const bf16* __restrict__ zn, const bf16* __restrict__ Q2T,
    const float* __restrict__ bq2,
    const int* __restrict__ src, const int* __restrict__ dst,
    const float* __restrict__ w,
    float* __restrict__ mout, float* __restrict__ wsum)
{
    __shared__ bf16 Zs[64 * 264];
    __shared__ int   dsts[64];
    __shared__ float wts[64];

    const int tid = threadIdx.x;
    const int lane = tid & 63, wave = tid >> 6;
    const size_t e0 = (size_t)blockIdx.x * 64;

    if (tid < 64) { dsts[tid] = dst[e0 + tid]; wts[tid] = w[e0 + tid]; }

    {   // gather 64 bf16 per thread-quarter (full coverage)
        const int r = tid >> 2, q = tid & 3;
        const int s = src[e0 + r];
        const bf16* zr = zn + (size_t)s * 256 + q * 64;
        bf16* zo = Zs + r * 264 + q * 64;
        #pragma unroll
        for (int i = 0; i < 16; ++i)
            *reinterpret_cast<ushort4*>(zo + i * 4) =
                *reinterpret_cast<const ushort4*>(zr + i * 4);
    }
    __syncthreads();

    const int lr = lane & 15;
    const int lk = (lane >> 4) * 8;
    const int lm4 = (lane >> 4) * 4;

    #pragma unroll
    for (int pass = 0; pass < 2; ++pass) {
        const int nc0 = wave * 128 + pass * 64;
        f32x4 acc[4][4];
        #pragma unroll
        for (int mi = 0; mi < 4; ++mi)
            #pragma unroll
            for (int ni = 0; ni < 4; ++ni) acc[mi][ni] = zero4();

        #pragma unroll
        for (int kk = 0; kk < 8; ++kk) {
            frag8 a[4], b[4];
            #pragma unroll
            for (int mi = 0; mi < 4; ++mi)
                a[mi] = *reinterpret_cast<const frag8*>(&Zs[(mi * 16 + lr) * 264 + kk * 32 + lk]);
            #pragma unroll
            for (int ni = 0; ni < 4; ++ni)
                b[ni] = *reinterpret_cast<const frag8*>(
                    Q2T + (size_t)(nc0 + ni * 16 + lr) * 256 + kk * 32 + lk);
            #pragma unroll
            for (int mi = 0; mi < 4; ++mi)
                #pragma unroll
                for (int ni = 0; ni < 4; ++ni)
                    acc[mi][ni] = mfma16(a[mi], b[ni], acc[mi][ni]);
        }
        #pragma unroll
        for (int ni = 0; ni < 4; ++ni) {
            const int c = nc0 + ni * 16 + lr;
            const float bb = bq2[c];
            #pragma unroll
            for (int mi = 0; mi < 4; ++mi)
                #pragma unroll
                for (int i = 0; i < 4; ++i) {
                    const int row = mi * 16 + lm4 + i;
                    const float val = fmaxf(acc[mi][ni][i] + bb, 0.f) * wts[row];
                    atomicAdd(&mout[(size_t)dsts[row] * 512 + c], val);
                }
        }
    }
    if (tid < 64) atomicAdd(&wsum[dsts[tid]], wts[tid]);
}

// ---------- l2 normalize rows of Z [rows,256] (bf16 in) -> bf16 out ----------
__global__ __launch_bounds__(256) void l2norm_kernel(
    const bf16* __restrict__ Z, bf16* __restrict__ out, int rows)
{
    const int wave = threadIdx.x >> 6, lane = threadIdx.x & 63;
    const int row = blockIdx.x * 4 + wave;
    if (row >= rows) return;
    const ushort4 u = *reinterpret_cast<const ushort4*>(Z + (size_t)row * 256 + lane * 4);
    float v[4] = { bfbits2f(u.x), bfbits2f(u.y), bfbits2f(u.z), bfbits2f(u.w) };
    float ss = v[0]*v[0] + v[1]*v[1] + v[2]*v[2] + v[3]*v[3];
    #pragma unroll
    for (int off = 32; off; off >>= 1) ss += __shfl_xor(ss, off, 64);
    const float scale = (ss == 0.f) ? 1.f : (1.f / sqrtf(ss));
    ushort4 o;
    o.x = f2bfbits(v[0]*scale); o.y = f2bfbits(v[1]*scale);
    o.z = f2bfbits(v[2]*scale); o.w = f2bfbits(v[3]*scale);
    *reinterpret_cast<ushort4*>(out + (size_t)row * 256 + lane * 4) = o;
}

// ---------- l2 normalize + skip add: out = P + Z/||Z|| (fp32) ----------
__global__ __launch_bounds__(256) void l2norm_add_kernel(
    const float* __restrict__ Z, const float* __restrict__ P,
    float* __restrict__ out, int rows)
{
    const int wave = threadIdx.x >> 6, lane = threadIdx.x & 63;
    const int row = blockIdx.x * 4 + wave;
    if (row >= rows) return;
    float v[4];
    load4f(Z + (size_t)row * 256 + lane * 4, v);
    float ss = v[0]*v[0] + v[1]*v[1] + v[2]*v[2] + v[3]*v[3];
    #pragma unroll
    for (int off = 32; off; off >>= 1) ss += __shfl_xor(ss, off, 64);
    const float scale = (ss == 0.f) ? 1.f : (1.f / sqrtf(ss));
    float p[4];
    load4f(P + (size_t)row * 256 + lane * 4, p);
    float4 o;
    o.x = p[0] + v[0]*scale; o.y = p[1] + v[1]*scale;
    o.z = p[2] + v[2]*scale; o.w = p[3] + v[3]*scale;
    *reinterpret_cast<float4*>(out + (size_t)row * 256 + lane * 4) = o;
}

// ---------- scoring: wave per edge; e<4096 -> pos, else neg. fp32 out ----------
__global__ __launch_bounds__(256) void score_kernel(
    const float* __restrict__ h,
    const int* __restrict__ ps, const int* __restrict__ pdi,
    const int* __restrict__ ns, const int* __restrict__ nd,
    const int* __restrict__ nid, const float* __restrict__ bias,
    float* __restrict__ out)
{
    const int wave = threadIdx.x >> 6, lane = threadIdx.x & 63;
    const int e = blockIdx.x * 4 + wave;
    const int ei = e & 4095;
    const int s = (e < 4096) ? ps[ei] : ns[ei];
    const int d = (e < 4096) ? pdi[ei] : nd[ei];
    float a[4], b[4];
    load4f(h + (size_t)s * 256 + lane * 4, a);
    load4f(h + (size_t)d * 256 + lane * 4, b);
    float dot = a[0]*b[0] + a[1]*b[1] + a[2]*b[2] + a[3]*b[3];
    #pragma unroll
    for (int off = 32; off; off >>= 1) dot += __shfl_xor(dot, off, 64);
    if (lane == 0)
        out[e] = dot + bias[nid[s]] + bias[nid[d]];
}

// ---------- launcher ----------
extern "C" void kernel_launch(void* const* d_in, const int* in_sizes, int n_in,
                              void* d_out, int out_size, void* d_ws, size_t ws_size,
                              hipStream_t stream)
{
    const float* feat0    = (const float*)d_in[0];
    const float* feat_dst = (const float*)d_in[1];
    const float* weights0 = (const float*)d_in[2];
    const float* weights1 = (const float*)d_in[3];
    const float* W_proj   = (const float*)d_in[4];
    const float* b_proj   = (const float*)d_in[5];
    const float* Q1       = (const float*)d_in[6];
    const float* bq1      = (const float*)d_in[7];
    const float* W1       = (const float*)d_in[8];
    const float* bw1      = (const float*)d_in[9];
    const float* Q2       = (const float*)d_in[10];
    const float* bq2      = (const float*)d_in[11];
    const float* W2       = (const float*)d_in[12];
    const float* bw2      = (const float*)d_in[13];
    const float* biasN    = (const float*)d_in[14];
    const int* b0s = (const int*)d_in[15];
    const int* b0d = (const int*)d_in[16];
    const int* b1s = (const int*)d_in[17];
    const int* b1d = (const int*)d_in[18];
    const int* pos_src = (const int*)d_in[19];
    const int* pos_dst = (const int*)d_in[20];
    const int* neg_src = (const int*)d_in[21];
    const int* neg_dst = (const int*)d_in[22];
    const int* nid     = (const int*)d_in[23];

    // ---- workspace layout (~110 MiB) ----
    char* ws = (char*)d_ws;
    size_t off = 0;
    auto alloc = [&](size_t bytes) -> void* {
        void* p = ws + off; off += (bytes + 255) & ~(size_t)255; return p;
    };
    float* m1    = (float*)alloc((size_t)N1c * 512 * 4);  // 75.50 MB (region1)
    bf16*  h1dst = (bf16*) alloc((size_t)N1c * 256 * 2);  // 18.87 MB (region2)
    bf16*  z1b   = (bf16*) alloc((size_t)N1c * 256 * 2);  // 18.87 MB
    float* ws0   = (float*)alloc((size_t)N1c * 4);        //  0.15 MB
    bf16*  WpT   = (bf16*) alloc((size_t)256 * 128 * 2);  // transposed bf16 weights
    bf16*  Q1T   = (bf16*) alloc((size_t)512 * 256 * 2);
    bf16*  Q2T   = (bf16*) alloc((size_t)512 * 256 * 2);
    bf16*  W1T   = (bf16*) alloc((size_t)256 * 768 * 2);
    bf16*  W2T   = (bf16*) alloc((size_t)256 * 768 * 2);

    // region1 reuse for layer 2 (m1 dead after W1-GEMM):
    char* r1 = (char*)m1;
    float* m2     = (float*)r1;                                   //  8.39 MB
    float* ws1    = (float*)(r1 + (size_t)N2c * 512 * 4);         //  16 KB
    float* z2     = (float*)(r1 + (size_t)N2c * 512 * 4 + 65536); //  4 MB
    float* pdbuf  = z2 + (size_t)N2c * 256;                       //  4 MB
    float* h_item = pdbuf + (size_t)N2c * 256;                    //  4 MB
    // region2 reuse: z1n aliases h1dst (h1dst dead after W1-GEMM)
    bf16* z1n = h1dst;

    // ---- prep: bf16 transposed weights ----
    transpose_bf16<<<(128*256 + 255)/256, 256, 0, stream>>>(W_proj, WpT, 128, 256);
    transpose_bf16<<<(256*512 + 255)/256, 256, 0, stream>>>(Q1, Q1T, 256, 512);
    transpose_bf16<<<(256*512 + 255)/256, 256, 0, stream>>>(Q2, Q2T, 256, 512);
    transpose_bf16<<<(768*256 + 255)/256, 256, 0, stream>>>(W1, W1T, 768, 256);
    transpose_bf16<<<(768*256 + 255)/256, 256, 0, stream>>>(W2, W2T, 768, 256);

    // ---- layer 1 ----
    hipMemsetAsync(m1,  0, (size_t)N1c * 512 * 4, stream);
    hipMemsetAsync(ws0, 0, (size_t)N1c * 4,       stream);

    gemm_mfma_proj<bf16><<<N1c/64, 256, 0, stream>>>(feat0, WpT, b_proj, h1dst);

    edge1_mfma<<<E0c/64, 256, 0, stream>>>(
        feat0, WpT, b_proj, Q1T, bq1, b0s, b0d, weights0, m1, ws0);

    gemm_mfma_concat<bf16><<<N1c/64, 256, 0, stream>>>(
        m1, ws0, h1dst, W1T, bw1, z1b);

    l2norm_kernel<<<N1c/4, 256, 0, stream>>>(z1b, z1n, N1c);  // z1n overwrites h1dst (dead)

    // ---- layer 2 (region1 now reusable) ----
    hipMemsetAsync(m2,  0, (size_t)N2c * 512 * 4, stream);
    hipMemsetAsync(ws1, 0, (size_t)N2c * 4,       stream);

    edge2_mfma<<<E1c/64, 256, 0, stream>>>(
        z1n, Q2T, bq2, b1s, b1d, weights1, m2, ws1);

    gemm_mfma_concat<float><<<N2c/64, 256, 0, stream>>>(
        m2, ws1, z1n, W2T, bw2, z2);

    gemm_mfma_proj<float><<<N2c/64, 256, 0, stream>>>(feat_dst, WpT, b_proj, pdbuf);

    l2norm_add_kernel<<<N2c/4, 256, 0, stream>>>(z2, pdbuf, h_item, N2c);

    score_kernel<<<2048, 256, 0, stream>>>(
        h_item, pos_src, pos_dst, neg_src, neg_dst, nid, biasN, (float*)d_out);
}